// Round 5
// baseline (347.305 us; speedup 1.0000x reference)
//
#include <hip/hip_runtime.h>
#include <hip/hip_bf16.h>

#define DIM   1024
#define NHEAD 16
#define HDIM  64
#define BATCH 4
#define SEQ   1024
#define MTOT  (BATCH*SEQ)   // 4096
#define DFF   (4*DIM)       // 4096
#define LDQ   3072          // fused QKV row stride

typedef _Float16 f16x8 __attribute__((ext_vector_type(8)));
typedef _Float16 f16x4 __attribute__((ext_vector_type(4)));
typedef float    f32x4 __attribute__((ext_vector_type(4)));

__device__ __forceinline__ float geluf(float x) {
    float x3 = x * x * x;
    return 0.5f * x * (1.0f + tanhf(0.7978845608028654f * (x + 0.044715f * x3)));
}

// Swizzled LDS byte offset for tiles with 64-f16 (128 B) rows, 8 slots of 16 B.
__device__ __forceinline__ int swz_off(int row, int slot) {
    return row * 128 + ((slot ^ (row & 7)) << 4);
}
__device__ __forceinline__ f16x8 ldsfrag(const _Float16* s, int row, int slot) {
    return *(const f16x8*)((const char*)s + swz_off(row, slot));
}

// Async global->LDS staging: linear LDS dest (wave-uniform base + lane*16),
// inverse-swizzled GLOBAL source so stored layout == swizzled layout (m173).
template <int NCHUNK>
__device__ __forceinline__ void stage_async(const _Float16* __restrict__ g, int ld,
                                            _Float16* s, int w, int lane) {
    int r_in = lane >> 3;               // 0..7 row within chunk
    int sslot = lane & 7;               // stored 16B slot
    int lslot = sslot ^ r_in;           // logical slot (row&7 == r_in)
#pragma unroll
    for (int q = 0; q < NCHUNK; ++q) {
        int chunk = w * NCHUNK + q;
        int row = chunk * 8 + r_in;
        const _Float16* gp = g + (size_t)row * ld + lslot * 8;
        _Float16* sp = s + chunk * 512;  // wave-uniform
        __builtin_amdgcn_global_load_lds(
            (const __attribute__((address_space(1))) void*)gp,
            (__attribute__((address_space(3))) void*)sp, 16, 0, 0);
    }
}

// ---------------- transpose + fp32->f16 convert:  src[K][N] -> dst[N][K] ----
__global__ __launch_bounds__(256) void k_tcvt(const float* __restrict__ src,
                                              _Float16* __restrict__ dst,
                                              int K, int N) {
    __shared__ float tile[32][33];
    int n0 = blockIdx.x * 32, k0 = blockIdx.y * 32;
    int tx = threadIdx.x, ty = threadIdx.y;
#pragma unroll
    for (int i = 0; i < 32; i += 8)
        tile[ty + i][tx] = src[(size_t)(k0 + ty + i) * N + (n0 + tx)];
    __syncthreads();
#pragma unroll
    for (int i = 0; i < 32; i += 8)
        dst[(size_t)(n0 + ty + i) * K + (k0 + tx)] = (_Float16)tile[tx][ty + i];
}

// three 1024x1024 transposes in one launch (z picks the source)
__global__ __launch_bounds__(256) void k_tcvt3(const float* __restrict__ s0,
                                               const float* __restrict__ s1,
                                               const float* __restrict__ s2,
                                               _Float16* __restrict__ dst) {
    __shared__ float tile[32][33];
    const float* src = blockIdx.z == 0 ? s0 : (blockIdx.z == 1 ? s1 : s2);
    _Float16* d = dst + (size_t)blockIdx.z * (1024 * 1024);
    int n0 = blockIdx.x * 32, k0 = blockIdx.y * 32;
    int tx = threadIdx.x, ty = threadIdx.y;
#pragma unroll
    for (int i = 0; i < 32; i += 8)
        tile[ty + i][tx] = src[(size_t)(k0 + ty + i) * 1024 + (n0 + tx)];
    __syncthreads();
#pragma unroll
    for (int i = 0; i < 32; i += 8)
        d[(size_t)(n0 + ty + i) * 1024 + (k0 + tx)] = (_Float16)tile[tx][ty + i];
}

// ---------------- LayerNorm (fp32 in -> f16 out), one block per row ---------
__global__ __launch_bounds__(256) void k_ln(const float* __restrict__ x,
                                            const float* __restrict__ sc,
                                            const float* __restrict__ sh,
                                            _Float16* __restrict__ out) {
    int row = blockIdx.x;
    int t = threadIdx.x;
    float4 v = ((const float4*)(x + (size_t)row * DIM))[t];
    float sum = v.x + v.y + v.z + v.w;
    float sq  = v.x * v.x + v.y * v.y + v.z * v.z + v.w * v.w;
#pragma unroll
    for (int m = 1; m < 64; m <<= 1) {
        sum += __shfl_xor(sum, m);
        sq  += __shfl_xor(sq, m);
    }
    __shared__ float rs[4], rq[4];
    int w = t >> 6;
    if ((t & 63) == 0) { rs[w] = sum; rq[w] = sq; }
    __syncthreads();
    sum = rs[0] + rs[1] + rs[2] + rs[3];
    sq  = rq[0] + rq[1] + rq[2] + rq[3];
    float mean = sum * (1.0f / DIM);
    float var  = sq * (1.0f / DIM) - mean * mean;
    float rstd = rsqrtf(var + 1e-5f);
    float4 s4 = ((const float4*)sc)[t];
    float4 b4 = ((const float4*)sh)[t];
    f16x4 o;
    o[0] = (_Float16)(s4.x * ((v.x - mean) * rstd) + b4.x);
    o[1] = (_Float16)(s4.y * ((v.y - mean) * rstd) + b4.y);
    o[2] = (_Float16)(s4.z * ((v.z - mean) * rstd) + b4.z);
    o[3] = (_Float16)(s4.w * ((v.w - mean) * rstd) + b4.w);
    ((f16x4*)(out + (size_t)row * DIM))[t] = o;
}

// ---------------- GEMM 128x128, BK=64, async-LDS staged ---------------------
// EPI: 0 = plain -> f16 out; 1 = +bias, gelu -> f16 out
template <int EPI>
__global__ __launch_bounds__(256) void k_gemm(const _Float16* __restrict__ A,
                                              const _Float16* __restrict__ BT,
                                              int M, int N, int K,
                                              _Float16* __restrict__ Ch,
                                              const float* __restrict__ bias) {
    __shared__ _Float16 As[128 * 64];
    __shared__ _Float16 Bs[128 * 64];
    int t = threadIdx.x;
    int m0 = blockIdx.y * 128, n0 = blockIdx.x * 128;
    int lane = t & 63, w = t >> 6;
    int wm = (w >> 1) * 64, wn = (w & 1) * 64;
    int lr = lane & 15, lg = lane >> 4;
    f32x4 acc[4][4];
#pragma unroll
    for (int i = 0; i < 4; ++i)
#pragma unroll
        for (int j = 0; j < 4; ++j) acc[i][j] = (f32x4){0.f, 0.f, 0.f, 0.f};

    const _Float16* Ag = A  + (size_t)m0 * K;
    const _Float16* Bg = BT + (size_t)n0 * K;
    for (int k0 = 0; k0 < K; k0 += 64) {
        stage_async<4>(Ag + k0, K, As, w, lane);
        stage_async<4>(Bg + k0, K, Bs, w, lane);
        __syncthreads();
#pragma unroll
        for (int kk = 0; kk < 2; ++kk) {
            f16x8 a[4], b[4];
#pragma unroll
            for (int i = 0; i < 4; ++i) a[i] = ldsfrag(As, wm + i * 16 + lr, kk * 4 + lg);
#pragma unroll
            for (int j = 0; j < 4; ++j) b[j] = ldsfrag(Bs, wn + j * 16 + lr, kk * 4 + lg);
#pragma unroll
            for (int i = 0; i < 4; ++i)
#pragma unroll
                for (int j = 0; j < 4; ++j)
                    acc[i][j] = __builtin_amdgcn_mfma_f32_16x16x32_f16(a[i], b[j], acc[i][j], 0, 0, 0);
        }
        __syncthreads();
    }
#pragma unroll
    for (int i = 0; i < 4; ++i) {
#pragma unroll
        for (int j = 0; j < 4; ++j) {
            int row = m0 + wm + i * 16 + lg * 4;
            int col = n0 + wn + j * 16 + lr;
#pragma unroll
            for (int r = 0; r < 4; ++r) {
                float v = acc[i][j][r];
                size_t idx = (size_t)(row + r) * N + col;
                if constexpr (EPI == 0) Ch[idx] = (_Float16)v;
                else                    Ch[idx] = (_Float16)geluf(v + bias[col]);
            }
        }
    }
}

// ---------------- GEMM 128x64 tile (for N=1024 outputs), +bias+resid f32 ----
__global__ __launch_bounds__(256) void k_gemm64(const _Float16* __restrict__ A,
                                                const _Float16* __restrict__ BT,
                                                int M, int N, int K,
                                                float* __restrict__ Cf,
                                                const float* __restrict__ bias,
                                                const float* __restrict__ resid) {
    __shared__ _Float16 As[128 * 64];
    __shared__ _Float16 Bs[64 * 64];
    int t = threadIdx.x;
    int m0 = blockIdx.y * 128, n0 = blockIdx.x * 64;
    int lane = t & 63, w = t >> 6;
    int wm = w * 32;
    int lr = lane & 15, lg = lane >> 4;
    f32x4 acc[2][4];
#pragma unroll
    for (int i = 0; i < 2; ++i)
#pragma unroll
        for (int j = 0; j < 4; ++j) acc[i][j] = (f32x4){0.f, 0.f, 0.f, 0.f};

    const _Float16* Ag = A  + (size_t)m0 * K;
    const _Float16* Bg = BT + (size_t)n0 * K;
    for (int k0 = 0; k0 < K; k0 += 64) {
        stage_async<4>(Ag + k0, K, As, w, lane);
        stage_async<2>(Bg + k0, K, Bs, w, lane);
        __syncthreads();
#pragma unroll
        for (int kk = 0; kk < 2; ++kk) {
            f16x8 a[2], b[4];
#pragma unroll
            for (int i = 0; i < 2; ++i) a[i] = ldsfrag(As, wm + i * 16 + lr, kk * 4 + lg);
#pragma unroll
            for (int j = 0; j < 4; ++j) b[j] = ldsfrag(Bs, j * 16 + lr, kk * 4 + lg);
#pragma unroll
            for (int i = 0; i < 2; ++i)
#pragma unroll
                for (int j = 0; j < 4; ++j)
                    acc[i][j] = __builtin_amdgcn_mfma_f32_16x16x32_f16(a[i], b[j], acc[i][j], 0, 0, 0);
        }
        __syncthreads();
    }
#pragma unroll
    for (int i = 0; i < 2; ++i) {
#pragma unroll
        for (int j = 0; j < 4; ++j) {
            int row = m0 + wm + i * 16 + lg * 4;
            int col = n0 + j * 16 + lr;
#pragma unroll
            for (int r = 0; r < 4; ++r) {
                size_t idx = (size_t)(row + r) * N + col;
                Cf[idx] = acc[i][j][r] + bias[col] + resid[idx];
            }
        }
    }
}

// ---------------- Flash attention helpers -----------------------------------
// Load one 64-wide K/V tile into registers (prefetch; used next phase).
__device__ __forceinline__ void attn_load(const _Float16* __restrict__ QKV,
                                          size_t base, int k0, int ck, int cv,
                                          int lane, int lr, int lg,
                                          f16x8 (&vreg)[8], f16x8 (&kreg)[8]) {
    const _Float16* vr = QKV + (base + k0 + lane) * LDQ + cv;
#pragma unroll
    for (int part = 0; part < 8; ++part)
        vreg[part] = *(const f16x8*)(vr + part * 8);
#pragma unroll
    for (int kk = 0; kk < 2; ++kk)
#pragma unroll
        for (int j = 0; j < 4; ++j)
            kreg[kk * 4 + j] = *(const f16x8*)(QKV + (base + k0 + j * 16 + lr) * LDQ + ck + kk * 32 + lg * 8);
}

// Process one 64-wide tile from registers.
__device__ __forceinline__ void attn_tile(const f16x8 (&vreg)[8], const f16x8 (&kreg)[8],
                                          const f16x8 (&aq)[2][2],
                                          f32x4 (&cacc)[2][4],
                                          float (&mrun)[2][4], float (&lrun)[2][4],
                                          _Float16* Vt, _Float16* Ps,
                                          int lane, int lr, int lg,
                                          bool diag, int q0, int k0) {
    // stage V^T into LDS (scalar transposed writes, swizzled)
    {
        int kslot = lane >> 3;
        int kb2 = (lane & 7) * 2;
#pragma unroll
        for (int part = 0; part < 8; ++part)
#pragma unroll
            for (int e = 0; e < 8; ++e) {
                int d = part * 8 + e;
                *(_Float16*)((char*)Vt + d * 128 + ((kslot ^ (d & 7)) << 4) + kb2) = vreg[part][e];
            }
    }
    // scores = Q K^T (K fragments already in registers)
    f32x4 sacc[2][4];
#pragma unroll
    for (int i = 0; i < 2; ++i)
#pragma unroll
        for (int j = 0; j < 4; ++j) sacc[i][j] = (f32x4){0.f, 0.f, 0.f, 0.f};
    __builtin_amdgcn_s_setprio(1);
#pragma unroll
    for (int kk = 0; kk < 2; ++kk)
#pragma unroll
        for (int i = 0; i < 2; ++i)
#pragma unroll
            for (int j = 0; j < 4; ++j)
                sacc[i][j] = __builtin_amdgcn_mfma_f32_16x16x32_f16(aq[i][kk], kreg[kk * 4 + j], sacc[i][j], 0, 0, 0);
    __builtin_amdgcn_s_setprio(0);
    // causal mask (diagonal tile only)
    if (diag) {
#pragma unroll
        for (int i = 0; i < 2; ++i)
#pragma unroll
            for (int j = 0; j < 4; ++j)
#pragma unroll
                for (int r = 0; r < 4; ++r) {
                    int qq = q0 + i * 16 + lg * 4 + r;
                    int kc = k0 + j * 16 + lr;
                    if (kc > qq) sacc[i][j][r] = -1e30f;
                }
    }
    // online softmax (rows spread over 16 lanes)
#pragma unroll
    for (int i = 0; i < 2; ++i) {
        float mn[4], al[4];
#pragma unroll
        for (int r = 0; r < 4; ++r) {
            float tm = fmaxf(fmaxf(sacc[i][0][r], sacc[i][1][r]),
                             fmaxf(sacc[i][2][r], sacc[i][3][r]));
#pragma unroll
            for (int msk = 1; msk < 16; msk <<= 1) tm = fmaxf(tm, __shfl_xor(tm, msk));
            float m2 = fmaxf(mrun[i][r], tm);
            al[r] = __expf(mrun[i][r] - m2);
            mrun[i][r] = m2;
            mn[r] = m2;
        }
#pragma unroll
        for (int jd = 0; jd < 4; ++jd)
#pragma unroll
            for (int r = 0; r < 4; ++r) cacc[i][jd][r] *= al[r];
#pragma unroll
        for (int r = 0; r < 4; ++r) {
            float ps = 0.f;
#pragma unroll
            for (int j = 0; j < 4; ++j) {
                float p = __expf(sacc[i][j][r] - mn[r]);
                sacc[i][j][r] = p;
                ps += p;
            }
#pragma unroll
            for (int msk = 1; msk < 16; msk <<= 1) ps += __shfl_xor(ps, msk);
            lrun[i][r] = lrun[i][r] * al[r] + ps;
        }
    }
    // P -> LDS (f16, swizzled A-operand layout)
#pragma unroll
    for (int i = 0; i < 2; ++i)
#pragma unroll
        for (int j = 0; j < 4; ++j) {
            int kc = j * 16 + lr;
            int ks = kc >> 3;
            int kb = (kc & 7) * 2;
#pragma unroll
            for (int r = 0; r < 4; ++r) {
                int qq = i * 16 + lg * 4 + r;
                *(_Float16*)((char*)Ps + qq * 128 + ((ks ^ (qq & 7)) << 4) + kb) =
                    (_Float16)sacc[i][j][r];
            }
        }
    // PV accumulate (same-wave LDS RAW; in-order per-wave DS pipe)
#pragma unroll
    for (int kk = 0; kk < 2; ++kk) {
        f16x8 pa[2], bv[4];
#pragma unroll
        for (int i = 0; i < 2; ++i)    pa[i]  = ldsfrag(Ps, i * 16 + lr,  kk * 4 + lg);
#pragma unroll
        for (int jd = 0; jd < 4; ++jd) bv[jd] = ldsfrag(Vt, jd * 16 + lr, kk * 4 + lg);
        __builtin_amdgcn_s_setprio(1);
#pragma unroll
        for (int i = 0; i < 2; ++i)
#pragma unroll
            for (int jd = 0; jd < 4; ++jd)
                cacc[i][jd] = __builtin_amdgcn_mfma_f32_16x16x32_f16(pa[i], bv[jd], cacc[i][jd], 0, 0, 0);
        __builtin_amdgcn_s_setprio(0);
    }
}

// ---------------- Flash attention: 1 wave per (b, h, 32-row q-tile) ---------
// Heavy-first 1D grid (LPT packing) + double-buffered register prefetch of
// next tile's K/V (T14). Barrier-free; each wave owns its rows end-to-end.
__global__ __launch_bounds__(64, 2) void k_attn(const _Float16* __restrict__ QKV,
                                                _Float16* __restrict__ Og) {
    __shared__ _Float16 Vt[64 * 64];  // V^T [d][k], swizzled (8 KB)
    __shared__ _Float16 Ps[32 * 64];  // P[q][k], swizzled (4 KB)
    int lane = threadIdx.x;
    int id = blockIdx.x;
    int bh = id & 63;
    int qt = (SEQ / 32 - 1) - (id >> 6);  // heavy blocks dispatch first
    int h = bh & 15, b = bh >> 4;
    int q0 = qt * 32;
    int lr = lane & 15, lg = lane >> 4;
    size_t base = (size_t)b * SEQ;
    int cq = h * HDIM, ck = 1024 + h * HDIM, cv = 2048 + h * HDIM;

    // Q fragments in registers, pre-scaled by 1/sqrt(HD)
    f16x8 aq[2][2];
#pragma unroll
    for (int i = 0; i < 2; ++i)
#pragma unroll
        for (int kk = 0; kk < 2; ++kk) {
            f16x8 v = *(const f16x8*)(QKV + (base + q0 + i * 16 + lr) * LDQ + cq + kk * 32 + lg * 8);
#pragma unroll
            for (int e = 0; e < 8; ++e) v[e] = v[e] * (_Float16)0.125f;
            aq[i][kk] = v;
        }

    f32x4 cacc[2][4];
#pragma unroll
    for (int i = 0; i < 2; ++i)
#pragma unroll
        for (int j = 0; j < 4; ++j) cacc[i][j] = (f32x4){0.f, 0.f, 0.f, 0.f};
    float mrun[2][4], lrun[2][4];
#pragma unroll
    for (int i = 0; i < 2; ++i)
#pragma unroll
        for (int r = 0; r < 4; ++r) { mrun[i][r] = -1e30f; lrun[i][r] = 0.f; }

    int ntiles = q0 / 64 + 1;   // 64-wide K/V tiles needed for causal rows
    f16x8 vA[8], kA[8], vB[8], kB[8];
    attn_load(QKV, base, 0, ck, cv, lane, lr, lg, vA, kA);
    for (int kt = 0; kt < ntiles; kt += 2) {
        if (kt + 1 < ntiles)
            attn_load(QKV, base, (kt + 1) * 64, ck, cv, lane, lr, lg, vB, kB);
        attn_tile(vA, kA, aq, cacc, mrun, lrun, Vt, Ps, lane, lr, lg,
                  kt == ntiles - 1, q0, kt * 64);
        if (kt + 1 >= ntiles) break;
        if (kt + 2 < ntiles)
            attn_load(QKV, base, (kt + 2) * 64, ck, cv, lane, lr, lg, vA, kA);
        attn_tile(vB, kB, aq, cacc, mrun, lrun, Vt, Ps, lane, lr, lg,
                  kt + 1 == ntiles - 1, q0, (kt + 1) * 64);
    }
    // normalize + write ctx in [b*S+s][h*64+d] layout
#pragma unroll
    for (int i = 0; i < 2; ++i)
#pragma unroll
        for (int jd = 0; jd < 4; ++jd)
#pragma unroll
            for (int r = 0; r < 4; ++r) {
                int qq = q0 + i * 16 + lg * 4 + r;
                int d = h * HDIM + jd * 16 + lr;
                Og[(base + qq) * DIM + d] = (_Float16)(cacc[i][jd][r] / lrun[i][r]);
            }
}

// ---------------------------------------------------------------------------
extern "C" void kernel_launch(void* const* d_in, const int* in_sizes, int n_in,
                              void* d_out, int out_size, void* d_ws, size_t ws_size,
                              hipStream_t stream) {
    const float* x    = (const float*)d_in[0];
    const float* WQ   = (const float*)d_in[1];
    const float* WK   = (const float*)d_in[2];
    const float* WV   = (const float*)d_in[3];
    const float* Wo   = (const float*)d_in[4];
    const float* bo   = (const float*)d_in[5];
    const float* W1   = (const float*)d_in[6];
    const float* b1   = (const float*)d_in[7];
    const float* W2   = (const float*)d_in[8];
    const float* b2   = (const float*)d_in[9];
    const float* ln1s = (const float*)d_in[10];
    const float* ln1b = (const float*)d_in[11];
    const float* ln2s = (const float*)d_in[12];
    const float* ln2b = (const float*)d_in[13];
    float* out = (float*)d_out;
    char* ws = (char*)d_ws;
    const size_t MB = 1024 * 1024;
    _Float16* WTqkv = (_Float16*)(ws + 0 * MB);   // [3072][1024] = 6MB
    _Float16* WTo   = (_Float16*)(ws + 6 * MB);
    _Float16* WT1   = (_Float16*)(ws + 8 * MB);   // [4096][1024]
    _Float16* WT2   = (_Float16*)(ws + 16 * MB);  // [1024][4096]
    _Float16* h1    = (_Float16*)(ws + 24 * MB);
    _Float16* qkvb  = (_Float16*)(ws + 32 * MB);  // [4096][3072] = 24MB
    _Float16* ctx   = (_Float16*)(ws + 56 * MB);
    _Float16* h2    = (_Float16*)(ws + 64 * MB);
    _Float16* ff1   = (_Float16*)(ws + 72 * MB);  // [4096][4096] = 32MB
    float*    x2    = (float*)   (ws + 104 * MB); // fp32 residual = 16MB

    dim3 tb(32, 8);
    k_tcvt3<<<dim3(32, 32, 3), tb, 0, stream>>>(WQ, WK, WV, WTqkv);
    k_tcvt<<<dim3(32, 32), tb, 0, stream>>>(Wo, WTo, 1024, 1024);
    k_tcvt<<<dim3(128, 32), tb, 0, stream>>>(W1, WT1, 1024, 4096);
    k_tcvt<<<dim3(32, 128), tb, 0, stream>>>(W2, WT2, 4096, 1024);

    k_ln<<<MTOT, 256, 0, stream>>>(x, ln1s, ln1b, h1);

    // fused QKV: [4096,1024] x [1024,3072] -> [4096,3072]
    k_gemm<0><<<dim3(24, 32), 256, 0, stream>>>(h1, WTqkv, MTOT, LDQ, DIM, qkvb, nullptr);

    k_attn<<<dim3(2048), 64, 0, stream>>>(qkvb, ctx);

    // x2 = x + ctx @ Wo + bo
    k_gemm64<<<dim3(16, 32), 256, 0, stream>>>(ctx, WTo, MTOT, DIM, DIM, x2, bo, x);

    k_ln<<<MTOT, 256, 0, stream>>>(x2, ln2s, ln2b, h2);

    // ff1 = gelu(h2 @ W1 + b1)
    k_gemm<1><<<dim3(32, 32), 256, 0, stream>>>(h2, WT1, MTOT, DFF, DIM, ff1, b1);

    // out = x2 + ff1 @ W2 + b2
    k_gemm64<<<dim3(16, 32), 256, 0, stream>>>(ff1, WT2, MTOT, DIM, DFF, out, b2, x2);
}

// Round 6
// 258.488 us; speedup vs baseline: 1.3436x; 1.3436x over previous
//
#include <hip/hip_runtime.h>
#include <hip/hip_bf16.h>

#define DIM   1024
#define NHEAD 16
#define HDIM  64
#define BATCH 4
#define SEQ   1024
#define MTOT  (BATCH*SEQ)   // 4096
#define DFF   (4*DIM)       // 4096
#define LDQ   3072          // fused QKV row stride

typedef _Float16 f16x8 __attribute__((ext_vector_type(8)));
typedef _Float16 f16x4 __attribute__((ext_vector_type(4)));
typedef float    f32x4 __attribute__((ext_vector_type(4)));

__device__ __forceinline__ float geluf(float x) {
    float x3 = x * x * x;
    return 0.5f * x * (1.0f + tanhf(0.7978845608028654f * (x + 0.044715f * x3)));
}

// Swizzled LDS byte offset for tiles with 64-f16 (128 B) rows, 8 slots of 16 B.
__device__ __forceinline__ int swz_off(int row, int slot) {
    return row * 128 + ((slot ^ (row & 7)) << 4);
}
__device__ __forceinline__ f16x8 ldsfrag(const _Float16* s, int row, int slot) {
    return *(const f16x8*)((const char*)s + swz_off(row, slot));
}

// Async global->LDS staging: linear LDS dest (wave-uniform base + lane*16),
// inverse-swizzled GLOBAL source so stored layout == swizzled layout (m173).
template <int NCHUNK>
__device__ __forceinline__ void stage_async(const _Float16* __restrict__ g, int ld,
                                            _Float16* s, int w, int lane) {
    int r_in = lane >> 3;               // 0..7 row within chunk
    int sslot = lane & 7;               // stored 16B slot
    int lslot = sslot ^ r_in;           // logical slot (row&7 == r_in)
#pragma unroll
    for (int q = 0; q < NCHUNK; ++q) {
        int chunk = w * NCHUNK + q;
        int row = chunk * 8 + r_in;
        const _Float16* gp = g + (size_t)row * ld + lslot * 8;
        _Float16* sp = s + chunk * 512;  // wave-uniform
        __builtin_amdgcn_global_load_lds(
            (const __attribute__((address_space(1))) void*)gp,
            (__attribute__((address_space(3))) void*)sp, 16, 0, 0);
    }
}

// ---------------- transpose + fp32->f16 convert:  src[K][N] -> dst[N][K] ----
__global__ __launch_bounds__(256) void k_tcvt(const float* __restrict__ src,
                                              _Float16* __restrict__ dst,
                                              int K, int N) {
    __shared__ float tile[32][33];
    int n0 = blockIdx.x * 32, k0 = blockIdx.y * 32;
    int tx = threadIdx.x, ty = threadIdx.y;
#pragma unroll
    for (int i = 0; i < 32; i += 8)
        tile[ty + i][tx] = src[(size_t)(k0 + ty + i) * N + (n0 + tx)];
    __syncthreads();
#pragma unroll
    for (int i = 0; i < 32; i += 8)
        dst[(size_t)(n0 + ty + i) * K + (k0 + tx)] = (_Float16)tile[tx][ty + i];
}

// three 1024x1024 transposes in one launch (z picks the source)
__global__ __launch_bounds__(256) void k_tcvt3(const float* __restrict__ s0,
                                               const float* __restrict__ s1,
                                               const float* __restrict__ s2,
                                               _Float16* __restrict__ dst) {
    __shared__ float tile[32][33];
    const float* src = blockIdx.z == 0 ? s0 : (blockIdx.z == 1 ? s1 : s2);
    _Float16* d = dst + (size_t)blockIdx.z * (1024 * 1024);
    int n0 = blockIdx.x * 32, k0 = blockIdx.y * 32;
    int tx = threadIdx.x, ty = threadIdx.y;
#pragma unroll
    for (int i = 0; i < 32; i += 8)
        tile[ty + i][tx] = src[(size_t)(k0 + ty + i) * 1024 + (n0 + tx)];
    __syncthreads();
#pragma unroll
    for (int i = 0; i < 32; i += 8)
        d[(size_t)(n0 + ty + i) * 1024 + (k0 + tx)] = (_Float16)tile[tx][ty + i];
}

// ---------------- LayerNorm (fp32 in -> f16 out), one block per row ---------
__global__ __launch_bounds__(256) void k_ln(const float* __restrict__ x,
                                            const float* __restrict__ sc,
                                            const float* __restrict__ sh,
                                            _Float16* __restrict__ out) {
    int row = blockIdx.x;
    int t = threadIdx.x;
    float4 v = ((const float4*)(x + (size_t)row * DIM))[t];
    float sum = v.x + v.y + v.z + v.w;
    float sq  = v.x * v.x + v.y * v.y + v.z * v.z + v.w * v.w;
#pragma unroll
    for (int m = 1; m < 64; m <<= 1) {
        sum += __shfl_xor(sum, m);
        sq  += __shfl_xor(sq, m);
    }
    __shared__ float rs[4], rq[4];
    int w = t >> 6;
    if ((t & 63) == 0) { rs[w] = sum; rq[w] = sq; }
    __syncthreads();
    sum = rs[0] + rs[1] + rs[2] + rs[3];
    sq  = rq[0] + rq[1] + rq[2] + rq[3];
    float mean = sum * (1.0f / DIM);
    float var  = sq * (1.0f / DIM) - mean * mean;
    float rstd = rsqrtf(var + 1e-5f);
    float4 s4 = ((const float4*)sc)[t];
    float4 b4 = ((const float4*)sh)[t];
    f16x4 o;
    o[0] = (_Float16)(s4.x * ((v.x - mean) * rstd) + b4.x);
    o[1] = (_Float16)(s4.y * ((v.y - mean) * rstd) + b4.y);
    o[2] = (_Float16)(s4.z * ((v.z - mean) * rstd) + b4.z);
    o[3] = (_Float16)(s4.w * ((v.w - mean) * rstd) + b4.w);
    ((f16x4*)(out + (size_t)row * DIM))[t] = o;
}

// ---------------- GEMM 128x128, BK=64, async-LDS staged ---------------------
// EPI: 0 = plain -> f16 out; 1 = +bias, gelu -> f16 out
template <int EPI>
__global__ __launch_bounds__(256) void k_gemm(const _Float16* __restrict__ A,
                                              const _Float16* __restrict__ BT,
                                              int M, int N, int K,
                                              _Float16* __restrict__ Ch,
                                              const float* __restrict__ bias) {
    __shared__ _Float16 As[128 * 64];
    __shared__ _Float16 Bs[128 * 64];
    int t = threadIdx.x;
    int m0 = blockIdx.y * 128, n0 = blockIdx.x * 128;
    int lane = t & 63, w = t >> 6;
    int wm = (w >> 1) * 64, wn = (w & 1) * 64;
    int lr = lane & 15, lg = lane >> 4;
    f32x4 acc[4][4];
#pragma unroll
    for (int i = 0; i < 4; ++i)
#pragma unroll
        for (int j = 0; j < 4; ++j) acc[i][j] = (f32x4){0.f, 0.f, 0.f, 0.f};

    const _Float16* Ag = A  + (size_t)m0 * K;
    const _Float16* Bg = BT + (size_t)n0 * K;
    for (int k0 = 0; k0 < K; k0 += 64) {
        stage_async<4>(Ag + k0, K, As, w, lane);
        stage_async<4>(Bg + k0, K, Bs, w, lane);
        __syncthreads();
#pragma unroll
        for (int kk = 0; kk < 2; ++kk) {
            f16x8 a[4], b[4];
#pragma unroll
            for (int i = 0; i < 4; ++i) a[i] = ldsfrag(As, wm + i * 16 + lr, kk * 4 + lg);
#pragma unroll
            for (int j = 0; j < 4; ++j) b[j] = ldsfrag(Bs, wn + j * 16 + lr, kk * 4 + lg);
#pragma unroll
            for (int i = 0; i < 4; ++i)
#pragma unroll
                for (int j = 0; j < 4; ++j)
                    acc[i][j] = __builtin_amdgcn_mfma_f32_16x16x32_f16(a[i], b[j], acc[i][j], 0, 0, 0);
        }
        __syncthreads();
    }
#pragma unroll
    for (int i = 0; i < 4; ++i) {
#pragma unroll
        for (int j = 0; j < 4; ++j) {
            int row = m0 + wm + i * 16 + lg * 4;
            int col = n0 + wn + j * 16 + lr;
#pragma unroll
            for (int r = 0; r < 4; ++r) {
                float v = acc[i][j][r];
                size_t idx = (size_t)(row + r) * N + col;
                if constexpr (EPI == 0) Ch[idx] = (_Float16)v;
                else                    Ch[idx] = (_Float16)geluf(v + bias[col]);
            }
        }
    }
}

// ---------------- GEMM 128x64 tile (for N=1024 outputs), +bias+resid f32 ----
__global__ __launch_bounds__(256) void k_gemm64(const _Float16* __restrict__ A,
                                                const _Float16* __restrict__ BT,
                                                int M, int N, int K,
                                                float* __restrict__ Cf,
                                                const float* __restrict__ bias,
                                                const float* __restrict__ resid) {
    __shared__ _Float16 As[128 * 64];
    __shared__ _Float16 Bs[64 * 64];
    int t = threadIdx.x;
    int m0 = blockIdx.y * 128, n0 = blockIdx.x * 64;
    int lane = t & 63, w = t >> 6;
    int wm = w * 32;
    int lr = lane & 15, lg = lane >> 4;
    f32x4 acc[2][4];
#pragma unroll
    for (int i = 0; i < 2; ++i)
#pragma unroll
        for (int j = 0; j < 4; ++j) acc[i][j] = (f32x4){0.f, 0.f, 0.f, 0.f};

    const _Float16* Ag = A  + (size_t)m0 * K;
    const _Float16* Bg = BT + (size_t)n0 * K;
    for (int k0 = 0; k0 < K; k0 += 64) {
        stage_async<4>(Ag + k0, K, As, w, lane);
        stage_async<2>(Bg + k0, K, Bs, w, lane);
        __syncthreads();
#pragma unroll
        for (int kk = 0; kk < 2; ++kk) {
            f16x8 a[2], b[4];
#pragma unroll
            for (int i = 0; i < 2; ++i) a[i] = ldsfrag(As, wm + i * 16 + lr, kk * 4 + lg);
#pragma unroll
            for (int j = 0; j < 4; ++j) b[j] = ldsfrag(Bs, j * 16 + lr, kk * 4 + lg);
#pragma unroll
            for (int i = 0; i < 2; ++i)
#pragma unroll
                for (int j = 0; j < 4; ++j)
                    acc[i][j] = __builtin_amdgcn_mfma_f32_16x16x32_f16(a[i], b[j], acc[i][j], 0, 0, 0);
        }
        __syncthreads();
    }
#pragma unroll
    for (int i = 0; i < 2; ++i) {
#pragma unroll
        for (int j = 0; j < 4; ++j) {
            int row = m0 + wm + i * 16 + lg * 4;
            int col = n0 + j * 16 + lr;
#pragma unroll
            for (int r = 0; r < 4; ++r) {
                size_t idx = (size_t)(row + r) * N + col;
                Cf[idx] = acc[i][j][r] + bias[col] + resid[idx];
            }
        }
    }
}

// ---------------- Flash attention: 1 wave per (b, h, 32-row q-tile) ---------
// R4's proven barrier-free structure + LPT heavy-first 1D grid (the only
// change vs R4): blocks with the most K/V tiles dispatch first, light ones
// backfill -> balanced makespan. NO register prefetch (R5 spilled).
__global__ __launch_bounds__(64) void k_attn(const _Float16* __restrict__ QKV,
                                             _Float16* __restrict__ Og) {
    __shared__ _Float16 Vt[64 * 64];  // V^T [d][k], swizzled (8 KB)
    __shared__ _Float16 Ps[32 * 64];  // P[q][k], swizzled (4 KB)
    int lane = threadIdx.x;
    int id = blockIdx.x;
    int bh = id & 63;
    int qt = (SEQ / 32 - 1) - (id >> 6);  // heavy blocks dispatch first
    int h = bh & 15, b = bh >> 4;
    int q0 = qt * 32;
    int lr = lane & 15, lg = lane >> 4;
    size_t base = (size_t)b * SEQ;
    int cq = h * HDIM, ck = 1024 + h * HDIM, cv = 2048 + h * HDIM;

    // Q fragments in registers, pre-scaled by 1/sqrt(HD)
    f16x8 aq[2][2];
#pragma unroll
    for (int i = 0; i < 2; ++i)
#pragma unroll
        for (int kk = 0; kk < 2; ++kk) {
            f16x8 v = *(const f16x8*)(QKV + (base + q0 + i * 16 + lr) * LDQ + cq + kk * 32 + lg * 8);
#pragma unroll
            for (int e = 0; e < 8; ++e) v[e] = v[e] * (_Float16)0.125f;
            aq[i][kk] = v;
        }

    f32x4 cacc[2][4];
#pragma unroll
    for (int i = 0; i < 2; ++i)
#pragma unroll
        for (int j = 0; j < 4; ++j) cacc[i][j] = (f32x4){0.f, 0.f, 0.f, 0.f};
    float mrun[2][4], lrun[2][4];
#pragma unroll
    for (int i = 0; i < 2; ++i)
#pragma unroll
        for (int r = 0; r < 4; ++r) { mrun[i][r] = -1e30f; lrun[i][r] = 0.f; }

    int ntiles = q0 / 64 + 1;   // 64-wide K/V tiles needed for causal rows
    for (int kt = 0; kt < ntiles; ++kt) {
        int k0 = kt * 64;
        // stage V^T into LDS (scalar transposed writes, swizzled; 2-way = free)
        {
            const _Float16* vr = QKV + (base + k0 + lane) * LDQ + cv;
            int kslot = lane >> 3;
            int kb2 = (lane & 7) * 2;
#pragma unroll
            for (int part = 0; part < 8; ++part) {
                f16x8 v8 = *(const f16x8*)(vr + part * 8);
#pragma unroll
                for (int e = 0; e < 8; ++e) {
                    int d = part * 8 + e;
                    *(_Float16*)((char*)Vt + d * 128 + ((kslot ^ (d & 7)) << 4) + kb2) = v8[e];
                }
            }
        }
        // scores = Q K^T (K fragments straight from global, L2-hot)
        f32x4 sacc[2][4];
#pragma unroll
        for (int i = 0; i < 2; ++i)
#pragma unroll
            for (int j = 0; j < 4; ++j) sacc[i][j] = (f32x4){0.f, 0.f, 0.f, 0.f};
#pragma unroll
        for (int kk = 0; kk < 2; ++kk) {
            f16x8 bk[4];
#pragma unroll
            for (int j = 0; j < 4; ++j)
                bk[j] = *(const f16x8*)(QKV + (base + k0 + j * 16 + lr) * LDQ + ck + kk * 32 + lg * 8);
            __builtin_amdgcn_s_setprio(1);
#pragma unroll
            for (int i = 0; i < 2; ++i)
#pragma unroll
                for (int j = 0; j < 4; ++j)
                    sacc[i][j] = __builtin_amdgcn_mfma_f32_16x16x32_f16(aq[i][kk], bk[j], sacc[i][j], 0, 0, 0);
            __builtin_amdgcn_s_setprio(0);
        }
        // causal mask (last tile only; global coords)
        if (kt == ntiles - 1) {
#pragma unroll
            for (int i = 0; i < 2; ++i)
#pragma unroll
                for (int j = 0; j < 4; ++j)
#pragma unroll
                    for (int r = 0; r < 4; ++r) {
                        int qq = q0 + i * 16 + lg * 4 + r;
                        int kc = k0 + j * 16 + lr;
                        if (kc > qq) sacc[i][j][r] = -1e30f;
                    }
        }
        // online softmax (rows spread over 16 lanes)
#pragma unroll
        for (int i = 0; i < 2; ++i) {
            float mn[4], al[4];
#pragma unroll
            for (int r = 0; r < 4; ++r) {
                float tm = fmaxf(fmaxf(sacc[i][0][r], sacc[i][1][r]),
                                 fmaxf(sacc[i][2][r], sacc[i][3][r]));
#pragma unroll
                for (int msk = 1; msk < 16; msk <<= 1) tm = fmaxf(tm, __shfl_xor(tm, msk));
                float m2 = fmaxf(mrun[i][r], tm);
                al[r] = __expf(mrun[i][r] - m2);
                mrun[i][r] = m2;
                mn[r] = m2;
            }
#pragma unroll
            for (int jd = 0; jd < 4; ++jd)
#pragma unroll
                for (int r = 0; r < 4; ++r) cacc[i][jd][r] *= al[r];
#pragma unroll
            for (int r = 0; r < 4; ++r) {
                float ps = 0.f;
#pragma unroll
                for (int j = 0; j < 4; ++j) {
                    float p = __expf(sacc[i][j][r] - mn[r]);
                    sacc[i][j][r] = p;
                    ps += p;
                }
#pragma unroll
                for (int msk = 1; msk < 16; msk <<= 1) ps += __shfl_xor(ps, msk);
                lrun[i][r] = lrun[i][r] * al[r] + ps;
            }
        }
        // P -> LDS (f16, swizzled A-operand layout)
#pragma unroll
        for (int i = 0; i < 2; ++i)
#pragma unroll
            for (int j = 0; j < 4; ++j) {
                int kc = j * 16 + lr;
                int ks = kc >> 3;
                int kb = (kc & 7) * 2;
#pragma unroll
                for (int r = 0; r < 4; ++r) {
                    int qq = i * 16 + lg * 4 + r;
                    *(_Float16*)((char*)Ps + qq * 128 + ((ks ^ (qq & 7)) << 4) + kb) =
                        (_Float16)sacc[i][j][r];
                }
            }
        // PV accumulate (same-wave LDS RAW; in-order per-wave DS pipe)
#pragma unroll
        for (int kk = 0; kk < 2; ++kk) {
            f16x8 pa[2], bv[4];
#pragma unroll
            for (int i = 0; i < 2; ++i)   pa[i]  = ldsfrag(Ps, i * 16 + lr,  kk * 4 + lg);
#pragma unroll
            for (int jd = 0; jd < 4; ++jd) bv[jd] = ldsfrag(Vt, jd * 16 + lr, kk * 4 + lg);
            __builtin_amdgcn_s_setprio(1);
#pragma unroll
            for (int i = 0; i < 2; ++i)
#pragma unroll
                for (int jd = 0; jd < 4; ++jd)
                    cacc[i][jd] = __builtin_amdgcn_mfma_f32_16x16x32_f16(pa[i], bv[jd], cacc[i][jd], 0, 0, 0);
            __builtin_amdgcn_s_setprio(0);
        }
    }
    // normalize + write ctx in [b*S+s][h*64+d] layout
#pragma unroll
    for (int i = 0; i < 2; ++i)
#pragma unroll
        for (int jd = 0; jd < 4; ++jd)
#pragma unroll
            for (int r = 0; r < 4; ++r) {
                int qq = q0 + i * 16 + lg * 4 + r;
                int d = h * HDIM + jd * 16 + lr;
                Og[(base + qq) * DIM + d] = (_Float16)(cacc[i][jd][r] / lrun[i][r]);
            }
}

// ---------------------------------------------------------------------------
extern "C" void kernel_launch(void* const* d_in, const int* in_sizes, int n_in,
                              void* d_out, int out_size, void* d_ws, size_t ws_size,
                              hipStream_t stream) {
    const float* x    = (const float*)d_in[0];
    const float* WQ   = (const float*)d_in[1];
    const float* WK   = (const float*)d_in[2];
    const float* WV   = (const float*)d_in[3];
    const float* Wo   = (const float*)d_in[4];
    const float* bo   = (const float*)d_in[5];
    const float* W1   = (const float*)d_in[6];
    const float* b1   = (const float*)d_in[7];
    const float* W2   = (const float*)d_in[8];
    const float* b2   = (const float*)d_in[9];
    const float* ln1s = (const float*)d_in[10];
    const float* ln1b = (const float*)d_in[11];
    const float* ln2s = (const float*)d_in[12];
    const float* ln2b = (const float*)d_in[13];
    float* out = (float*)d_out;
    char* ws = (char*)d_ws;
    const size_t MB = 1024 * 1024;
    _Float16* WTqkv = (_Float16*)(ws + 0 * MB);   // [3072][1024] = 6MB
    _Float16* WTo   = (_Float16*)(ws + 6 * MB);
    _Float16* WT1   = (_Float16*)(ws + 8 * MB);   // [4096][1024]
    _Float16* WT2   = (_Float16*)(ws + 16 * MB);  // [1024][4096]
    _Float16* h1    = (_Float16*)(ws + 24 * MB);
    _Float16* qkvb  = (_Float16*)(ws + 32 * MB);  // [4096][3072] = 24MB
    _Float16* ctx   = (_Float16*)(ws + 56 * MB);
    _Float16* h2    = (_Float16*)(ws + 64 * MB);
    _Float16* ff1   = (_Float16*)(ws + 72 * MB);  // [4096][4096] = 32MB
    float*    x2    = (float*)   (ws + 104 * MB); // fp32 residual = 16MB

    dim3 tb(32, 8);
    k_tcvt3<<<dim3(32, 32, 3), tb, 0, stream>>>(WQ, WK, WV, WTqkv);
    k_tcvt<<<dim3(32, 32), tb, 0, stream>>>(Wo, WTo, 1024, 1024);
    k_tcvt<<<dim3(128, 32), tb, 0, stream>>>(W1, WT1, 1024, 4096);
    k_tcvt<<<dim3(32, 128), tb, 0, stream>>>(W2, WT2, 4096, 1024);

    k_ln<<<MTOT, 256, 0, stream>>>(x, ln1s, ln1b, h1);

    // fused QKV: [4096,1024] x [1024,3072] -> [4096,3072]
    k_gemm<0><<<dim3(24, 32), 256, 0, stream>>>(h1, WTqkv, MTOT, LDQ, DIM, qkvb, nullptr);

    k_attn<<<dim3(2048), 64, 0, stream>>>(qkvb, ctx);

    // x2 = x + ctx @ Wo + bo
    k_gemm64<<<dim3(16, 32), 256, 0, stream>>>(ctx, WTo, MTOT, DIM, DIM, x2, bo, x);

    k_ln<<<MTOT, 256, 0, stream>>>(x2, ln2s, ln2b, h2);

    // ff1 = gelu(h2 @ W1 + b1)
    k_gemm<1><<<dim3(32, 32), 256, 0, stream>>>(h2, WT1, MTOT, DFF, DIM, ff1, b1);

    // out = x2 + ff1 @ W2 + b2
    k_gemm64<<<dim3(16, 32), 256, 0, stream>>>(ff1, WT2, MTOT, DIM, DFF, out, b2, x2);
}

// Round 7
// 245.486 us; speedup vs baseline: 1.4148x; 1.0530x over previous
//
#include <hip/hip_runtime.h>
#include <hip/hip_bf16.h>

#define DIM   1024
#define NHEAD 16
#define HDIM  64
#define BATCH 4
#define SEQ   1024
#define MTOT  (BATCH*SEQ)   // 4096
#define DFF   (4*DIM)       // 4096
#define LDQ   3072          // fused QKV row stride

typedef _Float16 f16x8 __attribute__((ext_vector_type(8)));
typedef _Float16 f16x4 __attribute__((ext_vector_type(4)));
typedef float    f32x4 __attribute__((ext_vector_type(4)));

// gelu(x) = 0.5x(1+tanh(z)) == x * sigmoid(2z), z = c(x + 0.044715 x^3).
// One v_exp + one v_rcp instead of libm tanhf (~25 ops).
__device__ __forceinline__ float geluf(float x) {
    float z2 = 1.5957691216057308f * (x + 0.044715f * x * x * x);  // 2*c*(...)
    return x * __builtin_amdgcn_rcpf(1.0f + __expf(-z2));
}

// Swizzled LDS byte offset for tiles with 64-f16 (128 B) rows, 8 slots of 16 B.
__device__ __forceinline__ int swz_off(int row, int slot) {
    return row * 128 + ((slot ^ (row & 7)) << 4);
}
__device__ __forceinline__ f16x8 ldsfrag(const _Float16* s, int row, int slot) {
    return *(const f16x8*)((const char*)s + swz_off(row, slot));
}

// Async global->LDS staging: linear LDS dest (wave-uniform base + lane*16),
// inverse-swizzled GLOBAL source so stored layout == swizzled layout (m173).
template <int NCHUNK>
__device__ __forceinline__ void stage_async(const _Float16* __restrict__ g, int ld,
                                            _Float16* s, int w, int lane) {
    int r_in = lane >> 3;               // 0..7 row within chunk
    int sslot = lane & 7;               // stored 16B slot
    int lslot = sslot ^ r_in;           // logical slot (row&7 == r_in)
#pragma unroll
    for (int q = 0; q < NCHUNK; ++q) {
        int chunk = w * NCHUNK + q;
        int row = chunk * 8 + r_in;
        const _Float16* gp = g + (size_t)row * ld + lslot * 8;
        _Float16* sp = s + chunk * 512;  // wave-uniform
        __builtin_amdgcn_global_load_lds(
            (const __attribute__((address_space(1))) void*)gp,
            (__attribute__((address_space(3))) void*)sp, 16, 0, 0);
    }
}

// ---------------- transpose + fp32->f16 convert:  src[K][N] -> dst[N][K] ----
__global__ __launch_bounds__(256) void k_tcvt(const float* __restrict__ src,
                                              _Float16* __restrict__ dst,
                                              int K, int N) {
    __shared__ float tile[32][33];
    int n0 = blockIdx.x * 32, k0 = blockIdx.y * 32;
    int tx = threadIdx.x, ty = threadIdx.y;
#pragma unroll
    for (int i = 0; i < 32; i += 8)
        tile[ty + i][tx] = src[(size_t)(k0 + ty + i) * N + (n0 + tx)];
    __syncthreads();
#pragma unroll
    for (int i = 0; i < 32; i += 8)
        dst[(size_t)(n0 + ty + i) * K + (k0 + tx)] = (_Float16)tile[tx][ty + i];
}

// three 1024x1024 transposes in one launch (z picks the source)
__global__ __launch_bounds__(256) void k_tcvt3(const float* __restrict__ s0,
                                               const float* __restrict__ s1,
                                               const float* __restrict__ s2,
                                               _Float16* __restrict__ dst) {
    __shared__ float tile[32][33];
    const float* src = blockIdx.z == 0 ? s0 : (blockIdx.z == 1 ? s1 : s2);
    _Float16* d = dst + (size_t)blockIdx.z * (1024 * 1024);
    int n0 = blockIdx.x * 32, k0 = blockIdx.y * 32;
    int tx = threadIdx.x, ty = threadIdx.y;
#pragma unroll
    for (int i = 0; i < 32; i += 8)
        tile[ty + i][tx] = src[(size_t)(k0 + ty + i) * 1024 + (n0 + tx)];
    __syncthreads();
#pragma unroll
    for (int i = 0; i < 32; i += 8)
        d[(size_t)(n0 + ty + i) * 1024 + (k0 + tx)] = (_Float16)tile[tx][ty + i];
}

// ---------------- LayerNorm (fp32 in -> f16 out), one block per row ---------
__global__ __launch_bounds__(256) void k_ln(const float* __restrict__ x,
                                            const float* __restrict__ sc,
                                            const float* __restrict__ sh,
                                            _Float16* __restrict__ out) {
    int row = blockIdx.x;
    int t = threadIdx.x;
    float4 v = ((const float4*)(x + (size_t)row * DIM))[t];
    float sum = v.x + v.y + v.z + v.w;
    float sq  = v.x * v.x + v.y * v.y + v.z * v.z + v.w * v.w;
#pragma unroll
    for (int m = 1; m < 64; m <<= 1) {
        sum += __shfl_xor(sum, m);
        sq  += __shfl_xor(sq, m);
    }
    __shared__ float rs[4], rq[4];
    int w = t >> 6;
    if ((t & 63) == 0) { rs[w] = sum; rq[w] = sq; }
    __syncthreads();
    sum = rs[0] + rs[1] + rs[2] + rs[3];
    sq  = rq[0] + rq[1] + rq[2] + rq[3];
    float mean = sum * (1.0f / DIM);
    float var  = sq * (1.0f / DIM) - mean * mean;
    float rstd = rsqrtf(var + 1e-5f);
    float4 s4 = ((const float4*)sc)[t];
    float4 b4 = ((const float4*)sh)[t];
    f16x4 o;
    o[0] = (_Float16)(s4.x * ((v.x - mean) * rstd) + b4.x);
    o[1] = (_Float16)(s4.y * ((v.y - mean) * rstd) + b4.y);
    o[2] = (_Float16)(s4.z * ((v.z - mean) * rstd) + b4.z);
    o[3] = (_Float16)(s4.w * ((v.w - mean) * rstd) + b4.w);
    ((f16x4*)(out + (size_t)row * DIM))[t] = o;
}

// ---------------- GEMM 128x128, BK=64, 2-phase pipelined (T3-min) -----------
// Per K-step: STAGE(next buf) -> compute(cur buf) -> one barrier (vmcnt drain
// doubles as buffer-ready handshake + reuse guard). Load latency hides under
// the MFMA cluster. EPI: 0 = plain -> f16 out; 1 = +bias, gelu -> f16 out
template <int EPI>
__global__ __launch_bounds__(256) void k_gemm(const _Float16* __restrict__ A,
                                              const _Float16* __restrict__ BT,
                                              int M, int N, int K,
                                              _Float16* __restrict__ Ch,
                                              const float* __restrict__ bias) {
    __shared__ _Float16 As[2][128 * 64];
    __shared__ _Float16 Bs[2][128 * 64];
    int t = threadIdx.x;
    int m0 = blockIdx.y * 128, n0 = blockIdx.x * 128;
    int lane = t & 63, w = t >> 6;
    int wm = (w >> 1) * 64, wn = (w & 1) * 64;
    int lr = lane & 15, lg = lane >> 4;
    f32x4 acc[4][4];
#pragma unroll
    for (int i = 0; i < 4; ++i)
#pragma unroll
        for (int j = 0; j < 4; ++j) acc[i][j] = (f32x4){0.f, 0.f, 0.f, 0.f};

    const _Float16* Ag = A  + (size_t)m0 * K;
    const _Float16* Bg = BT + (size_t)n0 * K;
    int nt = K / 64;
    stage_async<4>(Ag, K, As[0], w, lane);
    stage_async<4>(Bg, K, Bs[0], w, lane);
    __syncthreads();
    for (int tt = 0; tt < nt; ++tt) {
        int cur = tt & 1, nxt = cur ^ 1;
        if (tt + 1 < nt) {
            stage_async<4>(Ag + (tt + 1) * 64, K, As[nxt], w, lane);
            stage_async<4>(Bg + (tt + 1) * 64, K, Bs[nxt], w, lane);
        }
#pragma unroll
        for (int kk = 0; kk < 2; ++kk) {
            f16x8 a[4], b[4];
#pragma unroll
            for (int i = 0; i < 4; ++i) a[i] = ldsfrag(As[cur], wm + i * 16 + lr, kk * 4 + lg);
#pragma unroll
            for (int j = 0; j < 4; ++j) b[j] = ldsfrag(Bs[cur], wn + j * 16 + lr, kk * 4 + lg);
            __builtin_amdgcn_s_setprio(1);
#pragma unroll
            for (int i = 0; i < 4; ++i)
#pragma unroll
                for (int j = 0; j < 4; ++j)
                    acc[i][j] = __builtin_amdgcn_mfma_f32_16x16x32_f16(a[i], b[j], acc[i][j], 0, 0, 0);
            __builtin_amdgcn_s_setprio(0);
        }
        __syncthreads();   // drains next-tile loads; guards buffer reuse
    }
#pragma unroll
    for (int i = 0; i < 4; ++i) {
#pragma unroll
        for (int j = 0; j < 4; ++j) {
            int row = m0 + wm + i * 16 + lg * 4;
            int col = n0 + wn + j * 16 + lr;
#pragma unroll
            for (int r = 0; r < 4; ++r) {
                float v = acc[i][j][r];
                size_t idx = (size_t)(row + r) * N + col;
                if constexpr (EPI == 0) Ch[idx] = (_Float16)v;
                else                    Ch[idx] = (_Float16)geluf(v + bias[col]);
            }
        }
    }
}

// ---------------- GEMM 128x64 tile (N=1024 outputs), 2-phase, +bias+resid ---
__global__ __launch_bounds__(256) void k_gemm64(const _Float16* __restrict__ A,
                                                const _Float16* __restrict__ BT,
                                                int M, int N, int K,
                                                float* __restrict__ Cf,
                                                const float* __restrict__ bias,
                                                const float* __restrict__ resid) {
    __shared__ _Float16 As[2][128 * 64];
    __shared__ _Float16 Bs[2][64 * 64];
    int t = threadIdx.x;
    int m0 = blockIdx.y * 128, n0 = blockIdx.x * 64;
    int lane = t & 63, w = t >> 6;
    int wm = w * 32;
    int lr = lane & 15, lg = lane >> 4;
    f32x4 acc[2][4];
#pragma unroll
    for (int i = 0; i < 2; ++i)
#pragma unroll
        for (int j = 0; j < 4; ++j) acc[i][j] = (f32x4){0.f, 0.f, 0.f, 0.f};

    const _Float16* Ag = A  + (size_t)m0 * K;
    const _Float16* Bg = BT + (size_t)n0 * K;
    int nt = K / 64;
    stage_async<4>(Ag, K, As[0], w, lane);
    stage_async<2>(Bg, K, Bs[0], w, lane);
    __syncthreads();
    for (int tt = 0; tt < nt; ++tt) {
        int cur = tt & 1, nxt = cur ^ 1;
        if (tt + 1 < nt) {
            stage_async<4>(Ag + (tt + 1) * 64, K, As[nxt], w, lane);
            stage_async<2>(Bg + (tt + 1) * 64, K, Bs[nxt], w, lane);
        }
#pragma unroll
        for (int kk = 0; kk < 2; ++kk) {
            f16x8 a[2], b[4];
#pragma unroll
            for (int i = 0; i < 2; ++i) a[i] = ldsfrag(As[cur], wm + i * 16 + lr, kk * 4 + lg);
#pragma unroll
            for (int j = 0; j < 4; ++j) b[j] = ldsfrag(Bs[cur], j * 16 + lr, kk * 4 + lg);
            __builtin_amdgcn_s_setprio(1);
#pragma unroll
            for (int i = 0; i < 2; ++i)
#pragma unroll
                for (int j = 0; j < 4; ++j)
                    acc[i][j] = __builtin_amdgcn_mfma_f32_16x16x32_f16(a[i], b[j], acc[i][j], 0, 0, 0);
            __builtin_amdgcn_s_setprio(0);
        }
        __syncthreads();
    }
#pragma unroll
    for (int i = 0; i < 2; ++i) {
#pragma unroll
        for (int j = 0; j < 4; ++j) {
            int row = m0 + wm + i * 16 + lg * 4;
            int col = n0 + j * 16 + lr;
#pragma unroll
            for (int r = 0; r < 4; ++r) {
                size_t idx = (size_t)(row + r) * N + col;
                Cf[idx] = acc[i][j][r] + bias[col] + resid[idx];
            }
        }
    }
}

// ---------------- Flash attention: 1 wave per (b, h, 32-row q-tile) ---------
// Barrier-free per-wave structure + LPT heavy-first 1D grid.
__global__ __launch_bounds__(64) void k_attn(const _Float16* __restrict__ QKV,
                                             _Float16* __restrict__ Og) {
    __shared__ _Float16 Vt[64 * 64];  // V^T [d][k], swizzled (8 KB)
    __shared__ _Float16 Ps[32 * 64];  // P[q][k], swizzled (4 KB)
    int lane = threadIdx.x;
    int id = blockIdx.x;
    int bh = id & 63;
    int qt = (SEQ / 32 - 1) - (id >> 6);  // heavy blocks dispatch first
    int h = bh & 15, b = bh >> 4;
    int q0 = qt * 32;
    int lr = lane & 15, lg = lane >> 4;
    size_t base = (size_t)b * SEQ;
    int cq = h * HDIM, ck = 1024 + h * HDIM, cv = 2048 + h * HDIM;

    // Q fragments in registers, pre-scaled by 1/sqrt(HD)
    f16x8 aq[2][2];
#pragma unroll
    for (int i = 0; i < 2; ++i)
#pragma unroll
        for (int kk = 0; kk < 2; ++kk) {
            f16x8 v = *(const f16x8*)(QKV + (base + q0 + i * 16 + lr) * LDQ + cq + kk * 32 + lg * 8);
#pragma unroll
            for (int e = 0; e < 8; ++e) v[e] = v[e] * (_Float16)0.125f;
            aq[i][kk] = v;
        }

    f32x4 cacc[2][4];
#pragma unroll
    for (int i = 0; i < 2; ++i)
#pragma unroll
        for (int j = 0; j < 4; ++j) cacc[i][j] = (f32x4){0.f, 0.f, 0.f, 0.f};
    float mrun[2][4], lrun[2][4];
#pragma unroll
    for (int i = 0; i < 2; ++i)
#pragma unroll
        for (int r = 0; r < 4; ++r) { mrun[i][r] = -1e30f; lrun[i][r] = 0.f; }

    int ntiles = q0 / 64 + 1;   // 64-wide K/V tiles needed for causal rows
    for (int kt = 0; kt < ntiles; ++kt) {
        int k0 = kt * 64;
        // stage V^T into LDS (scalar transposed writes, swizzled; 2-way = free)
        {
            const _Float16* vr = QKV + (base + k0 + lane) * LDQ + cv;
            int kslot = lane >> 3;
            int kb2 = (lane & 7) * 2;
#pragma unroll
            for (int part = 0; part < 8; ++part) {
                f16x8 v8 = *(const f16x8*)(vr + part * 8);
#pragma unroll
                for (int e = 0; e < 8; ++e) {
                    int d = part * 8 + e;
                    *(_Float16*)((char*)Vt + d * 128 + ((kslot ^ (d & 7)) << 4) + kb2) = v8[e];
                }
            }
        }
        // scores = Q K^T (K fragments straight from global, L2-hot)
        f32x4 sacc[2][4];
#pragma unroll
        for (int i = 0; i < 2; ++i)
#pragma unroll
            for (int j = 0; j < 4; ++j) sacc[i][j] = (f32x4){0.f, 0.f, 0.f, 0.f};
#pragma unroll
        for (int kk = 0; kk < 2; ++kk) {
            f16x8 bk[4];
#pragma unroll
            for (int j = 0; j < 4; ++j)
                bk[j] = *(const f16x8*)(QKV + (base + k0 + j * 16 + lr) * LDQ + ck + kk * 32 + lg * 8);
            __builtin_amdgcn_s_setprio(1);
#pragma unroll
            for (int i = 0; i < 2; ++i)
#pragma unroll
                for (int j = 0; j < 4; ++j)
                    sacc[i][j] = __builtin_amdgcn_mfma_f32_16x16x32_f16(aq[i][kk], bk[j], sacc[i][j], 0, 0, 0);
            __builtin_amdgcn_s_setprio(0);
        }
        // causal mask (last tile only; global coords)
        if (kt == ntiles - 1) {
#pragma unroll
            for (int i = 0; i < 2; ++i)
#pragma unroll
                for (int j = 0; j < 4; ++j)
#pragma unroll
                    for (int r = 0; r < 4; ++r) {
                        int qq = q0 + i * 16 + lg * 4 + r;
                        int kc = k0 + j * 16 + lr;
                        if (kc > qq) sacc[i][j][r] = -1e30f;
                    }
        }
        // online softmax (rows spread over 16 lanes)
#pragma unroll
        for (int i = 0; i < 2; ++i) {
            float mn[4], al[4];
#pragma unroll
            for (int r = 0; r < 4; ++r) {
                float tm = fmaxf(fmaxf(sacc[i][0][r], sacc[i][1][r]),
                                 fmaxf(sacc[i][2][r], sacc[i][3][r]));
#pragma unroll
                for (int msk = 1; msk < 16; msk <<= 1) tm = fmaxf(tm, __shfl_xor(tm, msk));
                float m2 = fmaxf(mrun[i][r], tm);
                al[r] = __expf(mrun[i][r] - m2);
                mrun[i][r] = m2;
                mn[r] = m2;
            }
#pragma unroll
            for (int jd = 0; jd < 4; ++jd)
#pragma unroll
                for (int r = 0; r < 4; ++r) cacc[i][jd][r] *= al[r];
#pragma unroll
            for (int r = 0; r < 4; ++r) {
                float ps = 0.f;
#pragma unroll
                for (int j = 0; j < 4; ++j) {
                    float p = __expf(sacc[i][j][r] - mn[r]);
                    sacc[i][j][r] = p;
                    ps += p;
                }
#pragma unroll
                for (int msk = 1; msk < 16; msk <<= 1) ps += __shfl_xor(ps, msk);
                lrun[i][r] = lrun[i][r] * al[r] + ps;
            }
        }
        // P -> LDS (f16, swizzled A-operand layout)
#pragma unroll
        for (int i = 0; i < 2; ++i)
#pragma unroll
            for (int j = 0; j < 4; ++j) {
                int kc = j * 16 + lr;
                int ks = kc >> 3;
                int kb = (kc & 7) * 2;
#pragma unroll
                for (int r = 0; r < 4; ++r) {
                    int qq = i * 16 + lg * 4 + r;
                    *(_Float16*)((char*)Ps + qq * 128 + ((ks ^ (qq & 7)) << 4) + kb) =
                        (_Float16)sacc[i][j][r];
                }
            }
        // PV accumulate (same-wave LDS RAW; in-order per-wave DS pipe)
#pragma unroll
        for (int kk = 0; kk < 2; ++kk) {
            f16x8 pa[2], bv[4];
#pragma unroll
            for (int i = 0; i < 2; ++i)   pa[i]  = ldsfrag(Ps, i * 16 + lr,  kk * 4 + lg);
#pragma unroll
            for (int jd = 0; jd < 4; ++jd) bv[jd] = ldsfrag(Vt, jd * 16 + lr, kk * 4 + lg);
            __builtin_amdgcn_s_setprio(1);
#pragma unroll
            for (int i = 0; i < 2; ++i)
#pragma unroll
                for (int jd = 0; jd < 4; ++jd)
                    cacc[i][jd] = __builtin_amdgcn_mfma_f32_16x16x32_f16(pa[i], bv[jd], cacc[i][jd], 0, 0, 0);
            __builtin_amdgcn_s_setprio(0);
        }
    }
    // normalize + write ctx in [b*S+s][h*64+d] layout
#pragma unroll
    for (int i = 0; i < 2; ++i)
#pragma unroll
        for (int jd = 0; jd < 4; ++jd)
#pragma unroll
            for (int r = 0; r < 4; ++r) {
                int qq = q0 + i * 16 + lg * 4 + r;
                int d = h * HDIM + jd * 16 + lr;
                Og[(base + qq) * DIM + d] = (_Float16)(cacc[i][jd][r] / lrun[i][r]);
            }
}

// ---------------------------------------------------------------------------
extern "C" void kernel_launch(void* const* d_in, const int* in_sizes, int n_in,
                              void* d_out, int out_size, void* d_ws, size_t ws_size,
                              hipStream_t stream) {
    const float* x    = (const float*)d_in[0];
    const float* WQ   = (const float*)d_in[1];
    const float* WK   = (const float*)d_in[2];
    const float* WV   = (const float*)d_in[3];
    const float* Wo   = (const float*)d_in[4];
    const float* bo   = (const float*)d_in[5];
    const float* W1   = (const float*)d_in[6];
    const float* b1   = (const float*)d_in[7];
    const float* W2   = (const float*)d_in[8];
    const float* b2   = (const float*)d_in[9];
    const float* ln1s = (const float*)d_in[10];
    const float* ln1b = (const float*)d_in[11];
    const float* ln2s = (const float*)d_in[12];
    const float* ln2b = (const float*)d_in[13];
    float* out = (float*)d_out;
    char* ws = (char*)d_ws;
    const size_t MB = 1024 * 1024;
    _Float16* WTqkv = (_Float16*)(ws + 0 * MB);   // [3072][1024] = 6MB
    _Float16* WTo   = (_Float16*)(ws + 6 * MB);
    _Float16* WT1   = (_Float16*)(ws + 8 * MB);   // [4096][1024]
    _Float16* WT2   = (_Float16*)(ws + 16 * MB);  // [1024][4096]
    _Float16* h1    = (_Float16*)(ws + 24 * MB);
    _Float16* qkvb  = (_Float16*)(ws + 32 * MB);  // [4096][3072] = 24MB
    _Float16* ctx   = (_Float16*)(ws + 56 * MB);
    _Float16* h2    = (_Float16*)(ws + 64 * MB);
    _Float16* ff1   = (_Float16*)(ws + 72 * MB);  // [4096][4096] = 32MB
    float*    x2    = (float*)   (ws + 104 * MB); // fp32 residual = 16MB

    dim3 tb(32, 8);
    k_tcvt3<<<dim3(32, 32, 3), tb, 0, stream>>>(WQ, WK, WV, WTqkv);
    k_tcvt<<<dim3(32, 32), tb, 0, stream>>>(Wo, WTo, 1024, 1024);
    k_tcvt<<<dim3(128, 32), tb, 0, stream>>>(W1, WT1, 1024, 4096);
    k_tcvt<<<dim3(32, 128), tb, 0, stream>>>(W2, WT2, 4096, 1024);

    k_ln<<<MTOT, 256, 0, stream>>>(x, ln1s, ln1b, h1);

    // fused QKV: [4096,1024] x [1024,3072] -> [4096,3072]
    k_gemm<0><<<dim3(24, 32), 256, 0, stream>>>(h1, WTqkv, MTOT, LDQ, DIM, qkvb, nullptr);

    k_attn<<<dim3(2048), 64, 0, stream>>>(qkvb, ctx);

    // x2 = x + ctx @ Wo + bo
    k_gemm64<<<dim3(16, 32), 256, 0, stream>>>(ctx, WTo, MTOT, DIM, DIM, x2, bo, x);

    k_ln<<<MTOT, 256, 0, stream>>>(x2, ln2s, ln2b, h2);

    // ff1 = gelu(h2 @ W1 + b1)
    k_gemm<1><<<dim3(32, 32), 256, 0, stream>>>(h2, WT1, MTOT, DFF, DIM, ff1, b1);

    // out = x2 + ff1 @ W2 + b2
    k_gemm64<<<dim3(16, 32), 256, 0, stream>>>(ff1, WT2, MTOT, DIM, DFF, out, b2, x2);
}